// Round 1
// 283.590 us; speedup vs baseline: 2.2654x; 2.2654x over previous
//
#include <hip/hip_runtime.h>

// ---------------------------------------------------------------------------
// AttentiveStateMLP fused forward, MI355X (gfx950) — MFMA rewrite.
// WG = 256 threads (4 waves) handles 64 samples. All sample-shared GEMMs
// (encoder, token-proj, QKV, Wo, Wp) run on v_mfma_f32_16x16x32_f16 with
// fp16 fragments; attention (5x5, 4 heads) + softmax + LN stay on VALU in
// f32. Weights are pre-packed into B-fragment layout in ws by k_prep.
// Fragment-layout safety: A and B are packed with the SAME assumed
// (lane-group, elem)->k bijection (k = 8*(lane>>4)+e), so the MFMA result
// is exact under any intra-operand k-permutation of the real HW layout.
// C/D layout (col = lane&15, row = 4*(lane>>4)+reg) is the HW-verified one.
// ---------------------------------------------------------------------------

#define B_TOTAL 131072
#define NBLK    (B_TOTAL / 64)

typedef _Float16 f16;
typedef __attribute__((ext_vector_type(2))) _Float16 f16x2;
typedef __attribute__((ext_vector_type(8))) _Float16 f16x8;
typedef __attribute__((ext_vector_type(8))) __fp16   mfma8;
typedef __attribute__((ext_vector_type(4))) float    f32x4;

// ---- ws layout (u32 words) ------------------------------------------------
// B-fragment blocks: 1 KiB each = 64 lanes x 16 B (uint4 per lane).
#define W_EW    0        // encoder   : 9 nt x 2 ks              = 18 blk
#define W_TOKW  4608     // token proj: t0 4x2, t1..4 4x1        = 24 blk
#define W_QKVW  10752    // qkv       : t0 4h*3nt*2ks, else *1   = 72 blk
#define W_WOW   29184    // Wo per hd : 4h x 4nt (K=32, hi 0)    = 16 blk
#define W_WPW   33280    // Wp        : 8nt x 2ks                = 16 blk
#define W_ENCB  37376    // f32 enc bias [144]
#define W_TOKB  37520    // f32 pb_t + bo [5][64]
#define W_QKVB  37840    // f32 bqkv + Wqkv@pb_t [5][192]
#define W_BPB   38800    // f32 bp [128]
#define W_TOTAL 38928

__device__ __forceinline__ unsigned pk_rne(float a, float b) {
    f16x2 r; r.x = (_Float16)a; r.y = (_Float16)b;   // C cast = RNE
    return __builtin_bit_cast(unsigned, r);
}

// ---------------------------------------------------------------------------
// prep: pack all weights into B-fragment layout + fused biases.
// assumed operand map: lane l holds n = nt*16 + (l&15); elem e (0..7) holds
// k = ks*32 + 8*(l>>4) + e.  (uint4 per lane, halfword e order)
// ---------------------------------------------------------------------------
extern "C" __global__ void k_prep(
    const float* __restrict__ Wph, const float* __restrict__ bph,
    const float* __restrict__ Wob, const float* __restrict__ bob,
    const float* __restrict__ Wmi, const float* __restrict__ bmi,
    const float* __restrict__ Wpr, const float* __restrict__ bpr,
    const float* __restrict__ Wse, const float* __restrict__ bse,
    const float* __restrict__ Pph, const float* __restrict__ pbph,
    const float* __restrict__ Pob, const float* __restrict__ pbob,
    const float* __restrict__ Pmi, const float* __restrict__ pbmi,
    const float* __restrict__ Ppr, const float* __restrict__ pbpr,
    const float* __restrict__ Pse, const float* __restrict__ pbse,
    const float* __restrict__ Wqkv, const float* __restrict__ bqkv,
    const float* __restrict__ Wo,  const float* __restrict__ bo,
    const float* __restrict__ Wp,  const float* __restrict__ bp,
    unsigned* __restrict__ ws)
{
    int idx = blockIdx.x * 256 + threadIdx.x;
    if (idx >= W_TOTAL) return;
    float* wsf = (float*)ws;

    if (idx < W_TOKW) {                       // ---- encoder frags
        int w2 = idx, blk = w2 >> 8, r = w2 & 255, lane = r >> 2, pr = r & 3;
        int nt = blk >> 1, ks = blk & 1;
        int n = nt * 16 + (lane & 15);
        float v[2];
#pragma unroll
        for (int e = 0; e < 2; e++) {
            int k = ks * 32 + ((lane >> 4) << 3) + pr * 2 + e;
            float val = 0.f;
            if (n < 64)       { if (k < 29) val = Wph[n*29 + k]; }
            else if (n < 96)  { int kk = k - 29; if (kk >= 0 && kk < 15) val = Wob[(n-64)*15 + kk]; }
            else if (n < 112) { int kk = k - 44; if (kk >= 0 && kk < 8)  val = Wmi[(n-96)*8  + kk]; }
            else if (n < 128) { int kk = k - 52; if (kk >= 0 && kk < 3)  val = Wpr[(n-112)*3 + kk]; }
            else              { int kk = k - 55; if (kk >= 0 && kk < 3)  val = Wse[(n-128)*3 + kk]; }
            v[e] = val;
        }
        ws[idx] = pk_rne(v[0], v[1]);
    } else if (idx < W_QKVW) {                // ---- token-proj frags (P_t^T)
        int w2 = idx - W_TOKW, blk = w2 >> 8, r = w2 & 255, lane = r >> 2, pr = r & 3;
        int t, nt, ks;
        if (blk < 8) { t = 0; nt = blk >> 1; ks = blk & 1; }
        else         { t = 1 + ((blk - 8) >> 2); nt = (blk - 8) & 3; ks = 0; }
        const float* P = (t==0)?Pph:(t==1)?Pob:(t==2)?Pmi:(t==3)?Ppr:Pse;
        int d = (t==0)?64:(t==1)?32:16;
        int n = nt * 16 + (lane & 15);
        float v[2];
#pragma unroll
        for (int e = 0; e < 2; e++) {
            int k = ks * 32 + ((lane >> 4) << 3) + pr * 2 + e;
            v[e] = (k < d) ? P[n*d + k] : 0.f;
        }
        ws[idx] = pk_rne(v[0], v[1]);
    } else if (idx < W_WOW) {                 // ---- qkv frags ((Wqkv@P_t)^T)
        int w2 = idx - W_QKVW, blk = w2 >> 8, r = w2 & 255, lane = r >> 2, pr = r & 3;
        int t, b2;
        if (blk < 24) { t = 0; b2 = blk; }
        else          { t = 1 + (blk - 24) / 12; b2 = (blk - 24) % 12; }
        int h, nt, ks;
        if (t == 0) { h = b2 / 6; int rem = b2 % 6; nt = rem >> 1; ks = rem & 1; }
        else        { h = b2 / 3; nt = b2 % 3; ks = 0; }
        const float* P = (t==0)?Pph:(t==1)?Pob:(t==2)?Pmi:(t==3)?Ppr:Pse;
        int d = (t==0)?64:(t==1)?32:16;
        int c = nt * 64 + h * 16 + (lane & 15);   // col in qkv (q|k|v slice)
        float v[2] = {0.f, 0.f};
#pragma unroll
        for (int e = 0; e < 2; e++) {
            int k = ks * 32 + ((lane >> 4) << 3) + pr * 2 + e;
            if (k < d) {
                float s = 0.f;
                for (int u = 0; u < 64; u++) s += Wqkv[c*64 + u] * P[u*d + k];
                v[e] = s;
            }
        }
        ws[idx] = pk_rne(v[0], v[1]);
    } else if (idx < W_WPW) {                 // ---- Wo frags (K=32, k>=16 -> 0)
        int w2 = idx - W_WOW, blk = w2 >> 8, r = w2 & 255, lane = r >> 2, pr = r & 3;
        int h = blk >> 2, nt = blk & 3;
        int n = nt * 16 + (lane & 15);
        float v[2];
#pragma unroll
        for (int e = 0; e < 2; e++) {
            int k = ((lane >> 4) << 3) + pr * 2 + e;
            v[e] = (k < 16) ? Wo[n*64 + h*16 + k] : 0.f;
        }
        ws[idx] = pk_rne(v[0], v[1]);
    } else if (idx < W_ENCB) {                // ---- Wp frags
        int w2 = idx - W_WPW, blk = w2 >> 8, r = w2 & 255, lane = r >> 2, pr = r & 3;
        int nt = blk >> 1, ks = blk & 1;
        int n = nt * 16 + (lane & 15);
        float v[2];
#pragma unroll
        for (int e = 0; e < 2; e++) {
            int k = ks * 32 + ((lane >> 4) << 3) + pr * 2 + e;
            v[e] = Wp[n*64 + k];
        }
        ws[idx] = pk_rne(v[0], v[1]);
    } else if (idx < W_TOKB) {                // ---- encoder bias concat
        int n = idx - W_ENCB;
        wsf[idx] = (n<64)?bph[n]:(n<96)?bob[n-64]:(n<112)?bmi[n-96]:(n<128)?bpr[n-112]:bse[n-128];
    } else if (idx < W_QKVB) {                // ---- pb_t + bo
        int r = idx - W_TOKB, t = r >> 6, u = r & 63;
        const float* pb = (t==0)?pbph:(t==1)?pbob:(t==2)?pbmi:(t==3)?pbpr:pbse;
        wsf[idx] = pb[u] + bo[u];
    } else if (idx < W_BPB) {                 // ---- bqkv + Wqkv@pb_t
        int r = idx - W_QKVB, t = r / 192, c = r % 192;
        const float* pb = (t==0)?pbph:(t==1)?pbob:(t==2)?pbmi:(t==3)?pbpr:pbse;
        float s = bqkv[c];
        for (int u = 0; u < 64; u++) s += Wqkv[c*64 + u] * pb[u];
        wsf[idx] = s;
    } else {
        wsf[idx] = bp[idx - W_BPB];
    }
}

// ---------------------------------------------------------------------------
// main kernel helpers
// ---------------------------------------------------------------------------
__device__ __forceinline__ f32x4 MFMA(f16x8 a, f16x8 b, f32x4 c) {
    return __builtin_amdgcn_mfma_f32_16x16x32_f16(
        __builtin_bit_cast(mfma8, a), __builtin_bit_cast(mfma8, b), c, 0, 0, 0);
}

__device__ __forceinline__ f16x8 ldB(const unsigned* __restrict__ W, int wordBase, int blk, int lane) {
    uint4 v = *((const uint4*)(W + wordBase) + (blk * 64 + lane));
    return __builtin_bit_cast(f16x8, v);
}

// A-frag from LDS: 8 contiguous fp16 along k. strides (168/72) are chosen so
// that 16 rows at the same k land on distinct bank groups (2-way max = free).
__device__ __forceinline__ f16x8 ldA(const f16* p, int stride, int row, int kbase, int lg) {
    return *(const f16x8*)(p + row * stride + kbase + lg * 8);
}

// C-frag (col = l15, rows = 4*lg+reg) -> fp16 LDS [row][col]
__device__ __forceinline__ void stC16(f16* base, int stride, int m0, int col0,
                                      f32x4 c, int l15, int lg) {
    int col = col0 + l15;
    int r0  = m0 + lg * 4;
#pragma unroll
    for (int r = 0; r < 4; r++) base[(r0 + r) * stride + col] = (f16)c[r];
}

// ---------------------------------------------------------------------------
extern "C" __global__ void __launch_bounds__(256, 2) k_main(
    const float* __restrict__ x,
    const float* __restrict__ gamma, const float* __restrict__ beta,
    const unsigned* __restrict__ W, float* __restrict__ out)
{
    // LDS: f (persistent) + phase-sequenced union region
    __shared__ f16 f_lds[64 * 168];                       // 21504 B
    __shared__ __align__(16) char dyn_lds[41216];         // union region
    f16*      xb   = (f16*)dyn_lds;                       // [64][72]   (E input)
    f16*      qkv  = (f16*)dyn_lds;                       // [64][242]  (per head)
    unsigned* ctx  = (unsigned*)(dyn_lds + 30976);        // [320][8] dwords
    f16*      plA  = (f16*)dyn_lds;                       // [64][72]   (pooled)
    float*    outb = (float*)dyn_lds;                     // [64][128]

    const int tid  = threadIdx.x;
    const int lane = tid & 63;
    const int wv   = tid >> 6;          // wave id 0..3
    const int l15  = lane & 15;
    const int lg   = lane >> 4;

    const float* wsf   = (const float*)W;
    const float* encb  = wsf + W_ENCB;
    const float* tokbp = wsf + W_TOKB;
    const float* qkvbp = wsf + W_QKVB;
    const float* bpp   = wsf + W_BPB;

    // ---- phase 0: zero LDS pads, stage x -> xb (fp16) ---------------------
    {
        unsigned* du = (unsigned*)dyn_lds;
        for (int i = tid; i < 2304; i += 256) du[i] = 0;            // xb
        unsigned* fu = (unsigned*)f_lds;
        for (int i = tid; i < 5376; i += 256) fu[i] = 0;            // f pads
    }
    __syncthreads();
    {
        const float* xp = x + (size_t)blockIdx.x * (64 * 58);
        for (int i = tid; i < 3712; i += 256) {
            int s = i / 58, k = i - s * 58;
            xb[s * 72 + k] = (f16)xp[i];
        }
    }
    __syncthreads();

    // ---- phase 1: encoders via MFMA, relu, -> f_lds -----------------------
    {
        f32x4 accE[3][4];
#pragma unroll
        for (int i = 0; i < 3; i++) {
            int nt = wv + i * 4;
            if (nt < 9) {
                float be = encb[nt * 16 + l15];
#pragma unroll
                for (int mt = 0; mt < 4; mt++) accE[i][mt] = (f32x4){be, be, be, be};
            }
        }
#pragma unroll
        for (int ks = 0; ks < 2; ks++) {
            f16x8 a[4];
#pragma unroll
            for (int mt = 0; mt < 4; mt++) a[mt] = ldA(xb, 72, mt * 16 + l15, ks * 32, lg);
#pragma unroll
            for (int i = 0; i < 3; i++) {
                int nt = wv + i * 4;
                if (nt < 9) {
                    f16x8 b = ldB(W, W_EW, nt * 2 + ks, lane);
#pragma unroll
                    for (int mt = 0; mt < 4; mt++) accE[i][mt] = MFMA(a[mt], b, accE[i][mt]);
                }
            }
        }
#pragma unroll
        for (int i = 0; i < 3; i++) {
            int nt = wv + i * 4;
            if (nt < 9) {
#pragma unroll
                for (int mt = 0; mt < 4; mt++) {
                    f32x4 c = accE[i][mt];
#pragma unroll
                    for (int r = 0; r < 4; r++) c[r] = fmaxf(c[r], 0.f);
                    stC16(f_lds, 168, mt * 16, nt * 16, c, l15, lg);
                }
            }
        }
    }
    __syncthreads();

    // ---- persistent h-frags: h = tok + attn_out, rows t*64 + wv*16 + .. ---
    f32x4 hf[5][4];

    // token projection (C-init = pb+bo bias)
    {
#pragma unroll
        for (int t = 0; t < 5; t++)
#pragma unroll
            for (int nt = 0; nt < 4; nt++) {
                float bb = tokbp[t * 64 + nt * 16 + l15];
                hf[t][nt] = (f32x4){bb, bb, bb, bb};
            }
#pragma unroll
        for (int t = 0; t < 5; t++) {
            const int tokOff[5]  = {0, 64, 96, 112, 128};
            const int tokBase[5] = {0, 8, 12, 16, 20};
#pragma unroll
            for (int ks = 0; ks < 2; ks++) {
                if (ks == 0 || t == 0) {
                    f16x8 a = ldA(f_lds, 168, wv * 16 + l15, tokOff[t] + ks * 32, lg);
#pragma unroll
                    for (int nt = 0; nt < 4; nt++) {
                        int blk = (t == 0) ? (nt * 2 + ks) : (tokBase[t] + nt);
                        f16x8 b = ldB(W, W_TOKW, blk, lane);
                        hf[t][nt] = MFMA(a, b, hf[t][nt]);
                    }
                }
            }
        }
    }

    // ---- per-head helpers -------------------------------------------------
    auto do_qkv = [&](int h) {
        const int tokOff[5]  = {0, 64, 96, 112, 128};
        const int qkvBase[5] = {0, 24, 36, 48, 60};
#pragma unroll
        for (int t = 0; t < 5; t++) {
            f32x4 aq[3];
#pragma unroll
            for (int nt = 0; nt < 3; nt++) {
                float bb = qkvbp[t * 192 + nt * 64 + h * 16 + l15];
                aq[nt] = (f32x4){bb, bb, bb, bb};
            }
#pragma unroll
            for (int ks = 0; ks < 2; ks++) {
                if (ks == 0 || t == 0) {
                    f16x8 a = ldA(f_lds, 168, wv * 16 + l15, tokOff[t] + ks * 32, lg);
#pragma unroll
                    for (int nt = 0; nt < 3; nt++) {
                        int blk = qkvBase[t] + ((t == 0) ? (h * 6 + nt * 2 + ks) : (h * 3 + nt));
                        f16x8 b = ldB(W, W_QKVW, blk, lane);
                        aq[nt] = MFMA(a, b, aq[nt]);
                    }
                }
            }
#pragma unroll
            for (int nt = 0; nt < 3; nt++)
                stC16(qkv, 242, wv * 16, t * 48 + nt * 16, aq[nt], l15, lg);
        }
    };

    auto do_att = [&]() {
        const int s    = tid & 63;
        const int role = wv;                     // wave-uniform; role0 also row 4
        const f16x2* qr2 = (const f16x2*)(qkv + s * 242);
        float q0[16], q4[16];
#pragma unroll
        for (int d2 = 0; d2 < 8; d2++) {
            f16x2 p = qr2[role * 24 + d2];
            q0[2*d2] = (float)p.x; q0[2*d2+1] = (float)p.y;
        }
        if (role == 0) {
#pragma unroll
            for (int d2 = 0; d2 < 8; d2++) {
                f16x2 p = qr2[96 + d2];
                q4[2*d2] = (float)p.x; q4[2*d2+1] = (float)p.y;
            }
        }
        float p0[5], p4[5];
#pragma unroll
        for (int j = 0; j < 5; j++) {
            float a0 = 0.f, a4 = 0.f;
#pragma unroll
            for (int d2 = 0; d2 < 8; d2++) {
                f16x2 kp = qr2[j * 24 + 8 + d2];
                float k0 = (float)kp.x, k1 = (float)kp.y;
                a0 += q0[2*d2] * k0 + q0[2*d2+1] * k1;
                if (role == 0) a4 += q4[2*d2] * k0 + q4[2*d2+1] * k1;
            }
            p0[j] = a0 * 0.25f; p4[j] = a4 * 0.25f;
        }
        auto softmax5 = [](float* sc) {
            float m = fmaxf(fmaxf(fmaxf(sc[0], sc[1]), fmaxf(sc[2], sc[3])), sc[4]);
            float l = 0.f;
#pragma unroll
            for (int j = 0; j < 5; j++) { sc[j] = __expf(sc[j] - m); l += sc[j]; }
            float r = 1.f / l;
#pragma unroll
            for (int j = 0; j < 5; j++) sc[j] *= r;
        };
        softmax5(p0);
        if (role == 0) softmax5(p4);
        float c0[16], c4[16];
#pragma unroll
        for (int d = 0; d < 16; d++) { c0[d] = 0.f; c4[d] = 0.f; }
#pragma unroll
        for (int j = 0; j < 5; j++) {
#pragma unroll
            for (int d2 = 0; d2 < 8; d2++) {
                f16x2 vp = qr2[j * 24 + 16 + d2];
                float v0 = (float)vp.x, v1 = (float)vp.y;
                c0[2*d2]   += p0[j] * v0;
                c0[2*d2+1] += p0[j] * v1;
                if (role == 0) { c4[2*d2] += p4[j] * v0; c4[2*d2+1] += p4[j] * v1; }
            }
        }
        auto wrctx = [&](int i, const float* c) {
            int row = i * 64 + s;
            int vx  = ((row >> 2) & 3) << 1;     // even xor: keeps dword pairs intact
#pragma unroll
            for (int d2 = 0; d2 < 8; d2++)
                ctx[row * 8 + (d2 ^ vx)] = pk_rne(c[2*d2], c[2*d2+1]);
        };
        wrctx(role, c0);
        if (role == 0) wrctx(4, c4);
    };

    auto do_wo = [&](int h) {
        f16x8 bfr[4];
#pragma unroll
        for (int nt = 0; nt < 4; nt++) bfr[nt] = ldB(W, W_WOW, h * 4 + nt, lane);
#pragma unroll
        for (int t = 0; t < 5; t++) {
            int row = t * 64 + wv * 16 + l15;
            int vx  = ((row >> 2) & 3) << 1;
            // A-frag: k 0..15 = ctx (lane groups 0,1), k 16..31 = zeros
            uint2 a0 = *(const uint2*)&ctx[row * 8 + (((lg & 1) * 4 + 0) ^ vx)];
            uint2 a1 = *(const uint2*)&ctx[row * 8 + (((lg & 1) * 4 + 2) ^ vx)];
            if (lg >= 2) { a0.x = 0; a0.y = 0; a1.x = 0; a1.y = 0; }
            uint4 ua; ua.x = a0.x; ua.y = a0.y; ua.z = a1.x; ua.w = a1.y;
            f16x8 a = __builtin_bit_cast(f16x8, ua);
#pragma unroll
            for (int nt = 0; nt < 4; nt++) hf[t][nt] = MFMA(a, bfr[nt], hf[t][nt]);
        }
    };

    // ---- phase 2: head pipeline ------------------------------------------
    do_qkv(0);
    __syncthreads();
    for (int h = 0; h < 4; h++) {
        do_att();
        __syncthreads();
        do_wo(h);
        if (h < 3) do_qkv(h + 1);
        __syncthreads();
    }

    // ---- phase 3: LN per (sample, token) in-frag, pool over tokens --------
    float g4[4], b4[4];
#pragma unroll
    for (int nt = 0; nt < 4; nt++) { g4[nt] = gamma[nt * 16 + l15]; b4[nt] = beta[nt * 16 + l15]; }
    f32x4 pool[4];
#pragma unroll
    for (int nt = 0; nt < 4; nt++) pool[nt] = (f32x4){0.f, 0.f, 0.f, 0.f};
#pragma unroll
    for (int t = 0; t < 5; t++) {
#pragma unroll
        for (int r = 0; r < 4; r++) {
            float sm = hf[t][0][r] + hf[t][1][r] + hf[t][2][r] + hf[t][3][r];
            sm += __shfl_xor(sm, 1); sm += __shfl_xor(sm, 2);
            sm += __shfl_xor(sm, 4); sm += __shfl_xor(sm, 8);
            float mu = sm * 0.015625f;
            float vs = 0.f;
#pragma unroll
            for (int nt = 0; nt < 4; nt++) { float d = hf[t][nt][r] - mu; vs += d * d; }
            vs += __shfl_xor(vs, 1); vs += __shfl_xor(vs, 2);
            vs += __shfl_xor(vs, 4); vs += __shfl_xor(vs, 8);
            float rs = rsqrtf(vs * 0.015625f + 1e-5f);
#pragma unroll
            for (int nt = 0; nt < 4; nt++)
                pool[nt][r] += (hf[t][nt][r] - mu) * rs * g4[nt] + b4[nt];
        }
    }
#pragma unroll
    for (int nt = 0; nt < 4; nt++) {
        f32x4 c = pool[nt];
#pragma unroll
        for (int r = 0; r < 4; r++) c[r] *= 0.2f;
        stC16(plA, 72, wv * 16, nt * 16, c, l15, lg);
    }
    __syncthreads();

    // ---- phase 4: out = relu(pooled @ Wp^T + bp) via MFMA -----------------
    {
        f32x4 accP[8];
#pragma unroll
        for (int n2 = 0; n2 < 8; n2++) {
            float bb = bpp[n2 * 16 + l15];
            accP[n2] = (f32x4){bb, bb, bb, bb};
        }
#pragma unroll
        for (int ks = 0; ks < 2; ks++) {
            f16x8 a = ldA(plA, 72, wv * 16 + l15, ks * 32, lg);
#pragma unroll
            for (int n2 = 0; n2 < 8; n2++) {
                f16x8 b = ldB(W, W_WPW, n2 * 2 + ks, lane);
                accP[n2] = MFMA(a, b, accP[n2]);
            }
        }
        __syncthreads();   // all pooled-A reads done before outb overwrites region
#pragma unroll
        for (int n2 = 0; n2 < 8; n2++) {
#pragma unroll
            for (int r = 0; r < 4; r++) {
                int srow = wv * 16 + lg * 4 + r;
                int col  = n2 * 16 + l15;
                outb[srow * 128 + (col ^ (((srow >> 2) & 3) << 4))] = fmaxf(accP[n2][r], 0.f);
            }
        }
    }
    __syncthreads();

    // ---- phase 5: coalesced float4 store ----------------------------------
    {
        float* og = out + (size_t)blockIdx.x * (64 * 128);
#pragma unroll
        for (int it = 0; it < 8; it++) {
            int i = tid + it * 256;
            int srow = i >> 5;
            int c4   = (i & 31) << 2;
            float4 v = *(const float4*)&outb[srow * 128 + (c4 ^ (((srow >> 2) & 3) << 4))];
            *(float4*)(og + srow * 128 + c4) = v;
        }
    }
}

// ---------------------------------------------------------------------------
extern "C" void kernel_launch(void* const* d_in, const int* in_sizes, int n_in,
                              void* d_out, int out_size, void* d_ws, size_t ws_size,
                              hipStream_t stream)
{
    const float* x      = (const float*)d_in[0];
    const float* W_phys = (const float*)d_in[1];
    const float* b_phys = (const float*)d_in[2];
    const float* W_obj  = (const float*)d_in[3];
    const float* b_obj  = (const float*)d_in[4];
    const float* W_mine = (const float*)d_in[5];
    const float* b_mine = (const float*)d_in[6];
    const float* W_prog = (const float*)d_in[7];
    const float* b_prog = (const float*)d_in[8];
    const float* W_seq  = (const float*)d_in[9];
    const float* b_seq  = (const float*)d_in[10];
    const float* P_phys = (const float*)d_in[11];
    const float* pb_phys= (const float*)d_in[12];
    const float* P_obj  = (const float*)d_in[13];
    const float* pb_obj = (const float*)d_in[14];
    const float* P_mine = (const float*)d_in[15];
    const float* pb_mine= (const float*)d_in[16];
    const float* P_prog = (const float*)d_in[17];
    const float* pb_prog= (const float*)d_in[18];
    const float* P_seq  = (const float*)d_in[19];
    const float* pb_seq = (const float*)d_in[20];
    const float* Wqkv   = (const float*)d_in[21];
    const float* bqkv   = (const float*)d_in[22];
    const float* Wo     = (const float*)d_in[23];
    const float* bo     = (const float*)d_in[24];
    const float* gamma  = (const float*)d_in[25];
    const float* beta   = (const float*)d_in[26];
    const float* Wp     = (const float*)d_in[27];
    const float* bp     = (const float*)d_in[28];

    unsigned* ws = (unsigned*)d_ws;

    k_prep<<<(W_TOTAL + 255) / 256, 256, 0, stream>>>(
        W_phys, b_phys, W_obj, b_obj, W_mine, b_mine, W_prog, b_prog, W_seq, b_seq,
        P_phys, pb_phys, P_obj, pb_obj, P_mine, pb_mine, P_prog, pb_prog, P_seq, pb_seq,
        Wqkv, bqkv, Wo, bo, Wp, bp, ws);

    k_main<<<NBLK, 256, 0, stream>>>(x, gamma, beta, ws, (float*)d_out);
}